// Round 4
// baseline (360.362 us; speedup 1.0000x reference)
//
#include <hip/hip_runtime.h>
#include <hip/hip_fp16.h>

// 2-layer GCN, N=1M (< 2^20) nodes, E=10M edges, dims 2 -> 8 -> 2.
//
// Deterministic line-aligned counting sort by dst into NB=1024 buckets of
// 1024 nodes, then one WG per bucket accumulates in LDS (no global float
// atomics). Each (chunk,bucket) sub-range is padded to 16 edges (64B) so
// scatter writes are line-aligned and chunk-private (no cross-XCD RMW).
// Chunk size EPW is chosen at launch from ws_size: smaller chunks = more
// workgroups = better occupancy, at the cost of more pad slots.
// Messages are fp16 (xs = x*dinv as __half2, 4MB -> L2-resident gathers).
// Sentinel pad slots carry bit31 (skipped) and distributed low bits.

#define NB    1024
#define SHIFT 10
#define WMASK 1023u
#define IDXMASK 0x1FFFFFu

// ---------- sort pipeline ----------

__global__ void h_hist(const int* __restrict__ dst, int ne, int epw,
                       int* __restrict__ ghist) {
    __shared__ int h[NB];
    int c = blockIdx.x;
    int c0 = c * epw, c1 = min(c0 + epw, ne);
    for (int b = threadIdx.x; b < NB; b += blockDim.x) h[b] = 0;
    __syncthreads();
    int n4 = (c1 - c0) >> 2;
    const int4* d4 = (const int4*)(dst + c0);
    for (int g = threadIdx.x; g < n4; g += blockDim.x) {
        int4 d = d4[g];
        atomicAdd(&h[d.x >> SHIFT], 1);
        atomicAdd(&h[d.y >> SHIFT], 1);
        atomicAdd(&h[d.z >> SHIFT], 1);
        atomicAdd(&h[d.w >> SHIFT], 1);
    }
    for (int e = c0 + (n4 << 2) + threadIdx.x; e < c1; e += blockDim.x)
        atomicAdd(&h[dst[e] >> SHIFT], 1);
    __syncthreads();
    for (int b = threadIdx.x; b < NB; b += blockDim.x)
        ghist[c * NB + b] = (h[b] + 15) & ~15;     // 64B-aligned capacity
}

// Exclusive scan of each bucket's capacity column across chunks (nc <= 1024).
__global__ void h_colscan(int* __restrict__ ghist, int* __restrict__ tot, int nc) {
    __shared__ int buf[1024];
    int b = blockIdx.x;
    for (int c = threadIdx.x; c < nc; c += blockDim.x) buf[c] = ghist[c * NB + b];
    __syncthreads();
    if (threadIdx.x == 0) {
        int s = 0;
        for (int c = 0; c < nc; ++c) { int v = buf[c]; buf[c] = s; s += v; }
        tot[b] = s;
    }
    __syncthreads();
    for (int c = threadIdx.x; c < nc; c += blockDim.x) ghist[c * NB + b] = buf[c];
}

__global__ void s_scan(const int* __restrict__ tot, int* __restrict__ start) {
    __shared__ int buf[NB];
    int t = threadIdx.x;               // 1024 threads
    int own = tot[t];
    buf[t] = own;
    __syncthreads();
    for (int off = 1; off < NB; off <<= 1) {
        int add = (t >= off) ? buf[t - off] : 0;
        __syncthreads();
        buf[t] += add;
        __syncthreads();
    }
    start[t] = buf[t] - own;
    if (t == NB - 1) start[NB] = buf[NB - 1];
}

__global__ void h_scatter(const int* __restrict__ src, const int* __restrict__ dst,
                          int ne, int epw, const int* __restrict__ colx,
                          const int* __restrict__ start,
                          unsigned* __restrict__ sorted, unsigned sentbase) {
    __shared__ int wb[NB];
    __shared__ int run[NB];
    int c = blockIdx.x;
    int c0 = c * epw, c1 = min(c0 + epw, ne);
    for (int b = threadIdx.x; b < NB; b += blockDim.x) {
        wb[b] = start[b] + colx[c * NB + b];
        run[b] = 0;
    }
    __syncthreads();
    int n4 = (c1 - c0) >> 2;
    const int4* s4 = (const int4*)(src + c0);
    const int4* d4 = (const int4*)(dst + c0);
    for (int g = threadIdx.x; g < n4; g += blockDim.x) {
        int4 s = s4[g];
        int4 d = d4[g];
        {
            int b = d.x >> SHIFT; int off = atomicAdd(&run[b], 1);
            sorted[wb[b] + off] = ((unsigned)s.x << SHIFT) | ((unsigned)d.x & WMASK);
        }
        {
            int b = d.y >> SHIFT; int off = atomicAdd(&run[b], 1);
            sorted[wb[b] + off] = ((unsigned)s.y << SHIFT) | ((unsigned)d.y & WMASK);
        }
        {
            int b = d.z >> SHIFT; int off = atomicAdd(&run[b], 1);
            sorted[wb[b] + off] = ((unsigned)s.z << SHIFT) | ((unsigned)d.z & WMASK);
        }
        {
            int b = d.w >> SHIFT; int off = atomicAdd(&run[b], 1);
            sorted[wb[b] + off] = ((unsigned)s.w << SHIFT) | ((unsigned)d.w & WMASK);
        }
    }
    for (int e = c0 + (n4 << 2) + threadIdx.x; e < c1; e += blockDim.x) {
        int d = dst[e];
        int b = d >> SHIFT; int off = atomicAdd(&run[b], 1);
        sorted[wb[b] + off] = ((unsigned)src[e] << SHIFT) | ((unsigned)d & WMASK);
    }
    __syncthreads();
    for (int b = threadIdx.x; b < NB; b += blockDim.x) {
        int cnt = run[b];
        int cap = (cnt + 15) & ~15;
        int base = wb[b];
        for (int k = cnt; k < cap; ++k)
            sorted[base + k] = sentbase | (unsigned)(k & WMASK);  // distributed pads
    }
}

// Per-bucket in-degree (skip sentinels) -> dinv, pre-scaled fp16 xs.
__global__ void s_deg(const unsigned* __restrict__ sorted, const int* __restrict__ start,
                      const float2* __restrict__ x, float* __restrict__ dinv,
                      __half2* __restrict__ xs, int nn) {
    __shared__ int cnt[NB];
    int b = blockIdx.x;
    for (int i = threadIdx.x; i < NB; i += blockDim.x) cnt[i] = 0;
    __syncthreads();
    int e0 = start[b], e1 = start[b + 1];
    int n4 = (e1 - e0) >> 2;
    const uint4* sv = (const uint4*)(sorted + e0);
    for (int g = threadIdx.x; g < n4; g += blockDim.x) {
        uint4 v = sv[g];
        if (!(v.x >> 31)) atomicAdd(&cnt[v.x & WMASK], 1);
        if (!(v.y >> 31)) atomicAdd(&cnt[v.y & WMASK], 1);
        if (!(v.z >> 31)) atomicAdd(&cnt[v.z & WMASK], 1);
        if (!(v.w >> 31)) atomicAdd(&cnt[v.w & WMASK], 1);
    }
    __syncthreads();
    int base = b << SHIFT;
    for (int j = threadIdx.x; j < NB; j += blockDim.x) {
        int node = base + j;
        if (node < nn) {
            float di = rsqrtf((float)(cnt[j] + 1));   // +1 self-loop
            dinv[node] = di;
            float2 xv = x[node];
            xs[node] = __floats2half2_rn(xv.x * di, xv.y * di);
        }
    }
    if (b == 0 && threadIdx.x == 0) xs[nn] = __floats2half2_rn(0.f, 0.f);
}

// Per-bucket aggregation + fused epilogue.
// LAYER==1: A = di*(acc + feat[node]); h=relu(W1^T A+b1); out_h2 = (W2^T h)*di
// LAYER==2: out_f2 = di*(acc + feat[node]) + b2
template <int LAYER>
__global__ void s_agg(const unsigned* __restrict__ sorted, const int* __restrict__ start,
                      const __half2* __restrict__ feat, const float* __restrict__ dinv,
                      const float* __restrict__ W1, const float* __restrict__ b1,
                      const float* __restrict__ W2, const float* __restrict__ b2,
                      __half2* __restrict__ out_h2, float2* __restrict__ out_f2, int nn) {
    __shared__ float accx[NB];
    __shared__ float accy[NB];
    int b = blockIdx.x;
    for (int i = threadIdx.x; i < NB; i += blockDim.x) { accx[i] = 0.f; accy[i] = 0.f; }
    __syncthreads();
    int e0 = start[b], e1 = start[b + 1];
    int n4 = (e1 - e0) >> 2;
    const uint4* sv = (const uint4*)(sorted + e0);
    for (int g = threadIdx.x; g < n4; g += blockDim.x) {
        uint4 v = sv[g];
        if (!(v.x >> 31)) {
            float2 f = __half22float2(feat[(v.x >> SHIFT) & IDXMASK]); int j = v.x & WMASK;
            atomicAdd(&accx[j], f.x); atomicAdd(&accy[j], f.y);
        }
        if (!(v.y >> 31)) {
            float2 f = __half22float2(feat[(v.y >> SHIFT) & IDXMASK]); int j = v.y & WMASK;
            atomicAdd(&accx[j], f.x); atomicAdd(&accy[j], f.y);
        }
        if (!(v.z >> 31)) {
            float2 f = __half22float2(feat[(v.z >> SHIFT) & IDXMASK]); int j = v.z & WMASK;
            atomicAdd(&accx[j], f.x); atomicAdd(&accy[j], f.y);
        }
        if (!(v.w >> 31)) {
            float2 f = __half22float2(feat[(v.w >> SHIFT) & IDXMASK]); int j = v.w & WMASK;
            atomicAdd(&accx[j], f.x); atomicAdd(&accy[j], f.y);
        }
    }
    __syncthreads();
    int base = b << SHIFT;
    for (int j = threadIdx.x; j < NB; j += blockDim.x) {
        int node = base + j;
        if (node >= nn) continue;
        float di = dinv[node];
        float2 self = __half22float2(feat[node]);
        float ax = di * (accx[j] + self.x);
        float ay = di * (accy[j] + self.y);
        if (LAYER == 1) {
            float o0 = 0.f, o1 = 0.f;
#pragma unroll
            for (int k = 0; k < 8; ++k) {
                float hk = fmaxf(ax * W1[k] + ay * W1[8 + k] + b1[k], 0.f);
                o0 += hk * W2[2 * k + 0];
                o1 += hk * W2[2 * k + 1];
            }
            out_h2[node] = __floats2half2_rn(o0 * di, o1 * di);
        } else {
            out_f2[node] = make_float2(ax + b2[0], ay + b2[1]);
        }
    }
    if (LAYER == 1 && b == 0 && threadIdx.x == 0)
        out_h2[nn] = __floats2half2_rn(0.f, 0.f);
}

// ---------- fallback (round-1 algorithm, ~24 MB scratch) ----------

__global__ void k_deg(const int* __restrict__ dst, int* __restrict__ deg, int ne) {
    int i = blockIdx.x * blockDim.x + threadIdx.x;
    int stride = gridDim.x * blockDim.x;
    for (; i < ne; i += stride) atomicAdd(&deg[dst[i]], 1);
}
__global__ void k_dinv(const int* __restrict__ deg, float* __restrict__ dinv, int nn) {
    int i = blockIdx.x * blockDim.x + threadIdx.x;
    if (i < nn) dinv[i] = rsqrtf((float)(deg[i] + 1));
}
__global__ void k_edge2(const int* __restrict__ src, const int* __restrict__ dst,
                        const float* __restrict__ feat2, const float* __restrict__ dinv,
                        float* __restrict__ agg2, int ne) {
    int i = blockIdx.x * blockDim.x + threadIdx.x;
    int stride = gridDim.x * blockDim.x;
    for (; i < ne; i += stride) {
        int s = src[i], d = dst[i];
        float nrm = dinv[s] * dinv[d];
        float2 f = reinterpret_cast<const float2*>(feat2)[s];
        unsafeAtomicAdd(&agg2[2 * d + 0], nrm * f.x);
        unsafeAtomicAdd(&agg2[2 * d + 1], nrm * f.y);
    }
}
__global__ void k_mid(const float* __restrict__ x, const float* __restrict__ aggx,
                      const float* __restrict__ dinv,
                      const float* __restrict__ W1, const float* __restrict__ b1,
                      const float* __restrict__ W2, float* __restrict__ a2, int nn) {
    int i = blockIdx.x * blockDim.x + threadIdx.x;
    if (i >= nn) return;
    float di = dinv[i], di2 = di * di;
    float2 xsv = reinterpret_cast<const float2*>(x)[i];
    float ax = aggx[2 * i + 0] + di2 * xsv.x;
    float ay = aggx[2 * i + 1] + di2 * xsv.y;
    float o0 = 0.f, o1 = 0.f;
#pragma unroll
    for (int k = 0; k < 8; ++k) {
        float hk = fmaxf(ax * W1[k] + ay * W1[8 + k] + b1[k], 0.f);
        o0 += hk * W2[2 * k + 0];
        o1 += hk * W2[2 * k + 1];
    }
    a2[2 * i + 0] = o0;
    a2[2 * i + 1] = o1;
}
__global__ void k_out(const float* __restrict__ a2, const float* __restrict__ dinv,
                      const float* __restrict__ b2, float* __restrict__ out, int nn) {
    int i = blockIdx.x * blockDim.x + threadIdx.x;
    if (i >= nn) return;
    float di = dinv[i], di2 = di * di;
    out[2 * i + 0] = out[2 * i + 0] + di2 * a2[2 * i + 0] + b2[0];
    out[2 * i + 1] = out[2 * i + 1] + di2 * a2[2 * i + 1] + b2[1];
}

extern "C" void kernel_launch(void* const* d_in, const int* in_sizes, int n_in,
                              void* d_out, int out_size, void* d_ws, size_t ws_size,
                              hipStream_t stream) {
    const float* x  = (const float*)d_in[0];
    const int*   ei = (const int*)d_in[1];
    const float* W1 = (const float*)d_in[2];
    const float* b1 = (const float*)d_in[3];
    const float* W2 = (const float*)d_in[4];
    const float* b2 = (const float*)d_in[5];
    float* out = (float*)d_out;

    const int nn = in_sizes[0] / 2;
    const int ne = in_sizes[1] / 2;
    const int* src = ei;
    const int* dst = ei + ne;

    char* ws = (char*)d_ws;
    size_t off = 0;
    auto alloc = [&](size_t bytes) -> void* {
        void* p = ws + off;
        off += (bytes + 255) & ~size_t(255);
        return p;
    };

    // pick the smallest chunk (most parallelism) whose worst-case fits ws
    const int cand[3] = {16384, 32768, 65536};
    int epw = 0, nc = 0;
    size_t sorted_elems = 0;
    for (int i = 0; i < 3; ++i) {
        int nc_ = (ne + cand[i] - 1) / cand[i];
        if (nc_ > 1024) continue;
        size_t se = (size_t)ne + (size_t)nc_ * NB * 16;
        size_t need = se * 4 + (size_t)nn * 4 + 2 * ((size_t)nn + 1) * 4
                    + (size_t)nc_ * NB * 4 + (2 * NB + 1) * 4 + 16384;
        if (need <= ws_size) { epw = cand[i]; nc = nc_; sorted_elems = se; break; }
    }

    if (epw) {
        unsigned* sorted = (unsigned*)alloc(sorted_elems * 4);
        float*    dinv   = (float*)   alloc((size_t)nn * 4);
        __half2*  xs     = (__half2*) alloc(((size_t)nn + 1) * 4);
        __half2*  xs2    = (__half2*) alloc(((size_t)nn + 1) * 4);
        int*      ghist  = (int*)     alloc((size_t)nc * NB * 4);
        int*      tot    = (int*)     alloc(NB * 4);
        int*      start  = (int*)     alloc((NB + 1) * 4);

        unsigned sentbase = 0x80000000u | ((unsigned)nn << SHIFT);

        h_hist   <<<nc, 1024, 0, stream>>>(dst, ne, epw, ghist);
        h_colscan<<<NB, 256, 0, stream>>>(ghist, tot, nc);
        s_scan   <<<1, NB, 0, stream>>>(tot, start);
        h_scatter<<<nc, 1024, 0, stream>>>(src, dst, ne, epw, ghist, start, sorted, sentbase);
        s_deg    <<<NB, 512, 0, stream>>>(sorted, start, (const float2*)x, dinv, xs, nn);
        s_agg<1> <<<NB, 512, 0, stream>>>(sorted, start, xs, dinv, W1, b1, W2, b2,
                                          xs2, nullptr, nn);
        s_agg<2> <<<NB, 512, 0, stream>>>(sorted, start, xs2, dinv, W1, b1, W2, b2,
                                          nullptr, (float2*)out, nn);
    } else {
        // fallback: round-1 algorithm
        int*   deg  = (int*)  alloc((size_t)nn * 4);
        float* dinv = (float*)alloc((size_t)nn * 4);
        float* aggx = (float*)alloc((size_t)nn * 8);
        float* a2   = (float*)alloc((size_t)nn * 8);
        hipMemsetAsync(deg,  0, (size_t)nn * 4, stream);
        hipMemsetAsync(aggx, 0, (size_t)nn * 8, stream);
        hipMemsetAsync(d_out, 0, (size_t)nn * 8, stream);
        const int TB = 256;
        int egrid = (ne + TB - 1) / TB;
        int ngrid = (nn + TB - 1) / TB;
        k_deg  <<<egrid, TB, 0, stream>>>(dst, deg, ne);
        k_dinv <<<ngrid, TB, 0, stream>>>(deg, dinv, nn);
        k_edge2<<<egrid, TB, 0, stream>>>(src, dst, x, dinv, aggx, ne);
        k_mid  <<<ngrid, TB, 0, stream>>>(x, aggx, dinv, W1, b1, W2, a2, nn);
        k_edge2<<<egrid, TB, 0, stream>>>(src, dst, a2, dinv, out, ne);
        k_out  <<<ngrid, TB, 0, stream>>>(a2, dinv, b2, out, nn);
    }
}

// Round 5
// 300.014 us; speedup vs baseline: 1.2012x; 1.2012x over previous
//
#include <hip/hip_runtime.h>
#include <hip/hip_fp16.h>

// 2-layer GCN, N=1M (< 2^20) nodes, E=10M edges, dims 2 -> 8 -> 2.
//
// Deterministic line-aligned counting sort by dst into NB=1024 buckets of
// 1024 nodes, then one WG per bucket accumulates in LDS (no global float
// atomics). Scatter v3: per-chunk LDS reorder (radix-partition style) then
// LINEAR copy-out in padded index space -- every 64B line is bucket-pure and
// written exactly once by consecutive lanes (write amplification ~1, vs 3.5x
// for the random-order scattered stores of v2). Sentinel pads (bit31, skipped
// by consumers) are emitted inline by the same copy loop.
// Messages are fp16 (xs = x*dinv as __half2, 4MB -> L2-resident gathers).

#define NB    1024
#define SHIFT 10
#define WMASK 1023u
#define IDXMASK 0x1FFFFFu
#define EPW   16384
#define BLK   1024
#define MAXLINES ((EPW + 15 * NB) / 16)   // 1984 worst-case padded lines/chunk

// ---------- sort pipeline ----------

__global__ __launch_bounds__(1024) void h_hist(const int* __restrict__ dst, int ne,
                                               int* __restrict__ ghist) {
    __shared__ int h[NB];
    int c = blockIdx.x;
    int c0 = c * EPW, c1 = min(c0 + EPW, ne);
    for (int b = threadIdx.x; b < NB; b += BLK) h[b] = 0;
    __syncthreads();
    int n4 = (c1 - c0) >> 2;
    const int4* d4 = (const int4*)(dst + c0);
    for (int g = threadIdx.x; g < n4; g += BLK) {
        int4 d = d4[g];
        atomicAdd(&h[d.x >> SHIFT], 1);
        atomicAdd(&h[d.y >> SHIFT], 1);
        atomicAdd(&h[d.z >> SHIFT], 1);
        atomicAdd(&h[d.w >> SHIFT], 1);
    }
    for (int e = c0 + (n4 << 2) + threadIdx.x; e < c1; e += BLK)
        atomicAdd(&h[dst[e] >> SHIFT], 1);
    __syncthreads();
    for (int b = threadIdx.x; b < NB; b += BLK)
        ghist[c * NB + b] = (h[b] + 15) & ~15;     // 64B-aligned capacity
}

// Exclusive scan of each bucket's capacity column across chunks (nc <= 1024).
__global__ void h_colscan(int* __restrict__ ghist, int* __restrict__ tot, int nc) {
    __shared__ int buf[1024];
    int b = blockIdx.x;
    for (int c = threadIdx.x; c < nc; c += blockDim.x) buf[c] = ghist[c * NB + b];
    __syncthreads();
    if (threadIdx.x == 0) {
        int s = 0;
        for (int c = 0; c < nc; ++c) { int v = buf[c]; buf[c] = s; s += v; }
        tot[b] = s;
    }
    __syncthreads();
    for (int c = threadIdx.x; c < nc; c += blockDim.x) ghist[c * NB + b] = buf[c];
}

__global__ void s_scan(const int* __restrict__ tot, int* __restrict__ start) {
    __shared__ int buf[NB];
    int t = threadIdx.x;               // 1024 threads
    int own = tot[t];
    buf[t] = own;
    __syncthreads();
    for (int off = 1; off < NB; off <<= 1) {
        int add = (t >= off) ? buf[t - off] : 0;
        __syncthreads();
        buf[t] += add;
        __syncthreads();
    }
    start[t] = buf[t] - own;
    if (t == NB - 1) start[NB] = buf[NB - 1];
}

// Radix-partition scatter: LDS hist -> dual scan -> LDS reorder -> linear
// padded copy-out (full-line writes only).
__global__ __launch_bounds__(1024, 2) void h_scatter(
        const int* __restrict__ src, const int* __restrict__ dst, int ne,
        const int* __restrict__ colx, const int* __restrict__ start,
        unsigned* __restrict__ sorted, unsigned sentbase) {
    __shared__ unsigned reorder[EPW];          // 64KB (also scan scratch)
    __shared__ unsigned short lbase[NB + 1];   // compact exclusive scan
    __shared__ unsigned short cbase[NB + 1];   // padded exclusive scan
    __shared__ int hist[NB];                   // counts, then run counters
    __shared__ int gbase[NB];                  // global dest base per bucket
    __shared__ unsigned short line_bucket[MAXLINES];

    int c = blockIdx.x;
    int c0 = c * EPW;
    int cnt_edges = min(EPW, ne - c0);
    int t = threadIdx.x;               // == bucket id (BLK == NB)

    hist[t] = 0;
    gbase[t] = start[t] + colx[c * NB + t];
    __syncthreads();

    // Phase 1: histogram (dst only)
    int n4 = cnt_edges >> 2;
    const int4* d4 = (const int4*)(dst + c0);
    for (int g = t; g < n4; g += BLK) {
        int4 d = d4[g];
        atomicAdd(&hist[d.x >> SHIFT], 1);
        atomicAdd(&hist[d.y >> SHIFT], 1);
        atomicAdd(&hist[d.z >> SHIFT], 1);
        atomicAdd(&hist[d.w >> SHIFT], 1);
    }
    for (int i = (n4 << 2) + t; i < cnt_edges; i += BLK)
        atomicAdd(&hist[dst[c0 + i] >> SHIFT], 1);
    __syncthreads();

    // Phase 2: dual scan (compact count, padded capacity) over 1024 buckets
    int2* sb = (int2*)reorder;         // scan scratch in reorder space
    int h = hist[t];
    int cap = (h + 15) & ~15;
    sb[t] = make_int2(h, cap);
    __syncthreads();
    for (int o = 1; o < NB; o <<= 1) {
        int2 a = (t >= o) ? sb[t - o] : make_int2(0, 0);
        __syncthreads();
        sb[t].x += a.x; sb[t].y += a.y;
        __syncthreads();
    }
    int lb = sb[t].x - h;              // compact base
    int cb = sb[t].y - cap;            // padded base
    lbase[t] = (unsigned short)lb;
    cbase[t] = (unsigned short)cb;
    if (t == NB - 1) {
        lbase[NB] = (unsigned short)sb[t].x;
        cbase[NB] = (unsigned short)sb[t].y;
    }
    // line -> bucket map (padded lines are bucket-pure: cap % 16 == 0)
    for (int k = 0; k < (cap >> 4); ++k)
        line_bucket[(cb >> 4) + k] = (unsigned short)t;
    __syncthreads();
    hist[t] = 0;                       // reuse as run counters
    __syncthreads();

    // Phase 3: rank + stage into LDS (re-read src+dst, L2-hot)
    const int4* s4 = (const int4*)(src + c0);
    for (int g = t; g < n4; g += BLK) {
        int4 s = s4[g];
        int4 d = d4[g];
        {
            int b = d.x >> SHIFT; int r = lbase[b] + atomicAdd(&hist[b], 1);
            reorder[r] = ((unsigned)s.x << SHIFT) | ((unsigned)d.x & WMASK);
        }
        {
            int b = d.y >> SHIFT; int r = lbase[b] + atomicAdd(&hist[b], 1);
            reorder[r] = ((unsigned)s.y << SHIFT) | ((unsigned)d.y & WMASK);
        }
        {
            int b = d.z >> SHIFT; int r = lbase[b] + atomicAdd(&hist[b], 1);
            reorder[r] = ((unsigned)s.z << SHIFT) | ((unsigned)d.z & WMASK);
        }
        {
            int b = d.w >> SHIFT; int r = lbase[b] + atomicAdd(&hist[b], 1);
            reorder[r] = ((unsigned)s.w << SHIFT) | ((unsigned)d.w & WMASK);
        }
    }
    for (int i = (n4 << 2) + t; i < cnt_edges; i += BLK) {
        int dd = dst[c0 + i], ss = src[c0 + i];
        int b = dd >> SHIFT; int r = lbase[b] + atomicAdd(&hist[b], 1);
        reorder[r] = ((unsigned)ss << SHIFT) | ((unsigned)dd & WMASK);
    }
    __syncthreads();

    // Phase 4: linear copy-out in padded index space. Every 64B line is
    // bucket-pure and written once, fully, by consecutive lanes.
    int ptot = cbase[NB];
    for (int p = t; p < ptot; p += BLK) {
        int b = line_bucket[p >> 4];
        int off = p - cbase[b];
        int cnt = lbase[b + 1] - lbase[b];
        unsigned v = (off < cnt) ? reorder[lbase[b] + off]
                                 : (sentbase | (unsigned)(off & WMASK));
        sorted[gbase[b] + off] = v;
    }
}

// Per-bucket in-degree (skip sentinels) -> dinv, pre-scaled fp16 xs.
__global__ void s_deg(const unsigned* __restrict__ sorted, const int* __restrict__ start,
                      const float2* __restrict__ x, float* __restrict__ dinv,
                      __half2* __restrict__ xs, int nn) {
    __shared__ int cnt[NB];
    int b = blockIdx.x;
    for (int i = threadIdx.x; i < NB; i += blockDim.x) cnt[i] = 0;
    __syncthreads();
    int e0 = start[b], e1 = start[b + 1];
    int n4 = (e1 - e0) >> 2;
    const uint4* sv = (const uint4*)(sorted + e0);
    for (int g = threadIdx.x; g < n4; g += blockDim.x) {
        uint4 v = sv[g];
        if (!(v.x >> 31)) atomicAdd(&cnt[v.x & WMASK], 1);
        if (!(v.y >> 31)) atomicAdd(&cnt[v.y & WMASK], 1);
        if (!(v.z >> 31)) atomicAdd(&cnt[v.z & WMASK], 1);
        if (!(v.w >> 31)) atomicAdd(&cnt[v.w & WMASK], 1);
    }
    __syncthreads();
    int base = b << SHIFT;
    for (int j = threadIdx.x; j < NB; j += blockDim.x) {
        int node = base + j;
        if (node < nn) {
            float di = rsqrtf((float)(cnt[j] + 1));   // +1 self-loop
            dinv[node] = di;
            float2 xv = x[node];
            xs[node] = __floats2half2_rn(xv.x * di, xv.y * di);
        }
    }
    if (b == 0 && threadIdx.x == 0) xs[nn] = __floats2half2_rn(0.f, 0.f);
}

// Per-bucket aggregation + fused epilogue.
// LAYER==1: A = di*(acc + feat[node]); h=relu(W1^T A+b1); out_h2 = (W2^T h)*di
// LAYER==2: out_f2 = di*(acc + feat[node]) + b2
template <int LAYER>
__global__ void s_agg(const unsigned* __restrict__ sorted, const int* __restrict__ start,
                      const __half2* __restrict__ feat, const float* __restrict__ dinv,
                      const float* __restrict__ W1, const float* __restrict__ b1,
                      const float* __restrict__ W2, const float* __restrict__ b2,
                      __half2* __restrict__ out_h2, float2* __restrict__ out_f2, int nn) {
    __shared__ float accx[NB];
    __shared__ float accy[NB];
    int b = blockIdx.x;
    for (int i = threadIdx.x; i < NB; i += blockDim.x) { accx[i] = 0.f; accy[i] = 0.f; }
    __syncthreads();
    int e0 = start[b], e1 = start[b + 1];
    int n4 = (e1 - e0) >> 2;
    const uint4* sv = (const uint4*)(sorted + e0);
    for (int g = threadIdx.x; g < n4; g += blockDim.x) {
        uint4 v = sv[g];
        if (!(v.x >> 31)) {
            float2 f = __half22float2(feat[(v.x >> SHIFT) & IDXMASK]); int j = v.x & WMASK;
            atomicAdd(&accx[j], f.x); atomicAdd(&accy[j], f.y);
        }
        if (!(v.y >> 31)) {
            float2 f = __half22float2(feat[(v.y >> SHIFT) & IDXMASK]); int j = v.y & WMASK;
            atomicAdd(&accx[j], f.x); atomicAdd(&accy[j], f.y);
        }
        if (!(v.z >> 31)) {
            float2 f = __half22float2(feat[(v.z >> SHIFT) & IDXMASK]); int j = v.z & WMASK;
            atomicAdd(&accx[j], f.x); atomicAdd(&accy[j], f.y);
        }
        if (!(v.w >> 31)) {
            float2 f = __half22float2(feat[(v.w >> SHIFT) & IDXMASK]); int j = v.w & WMASK;
            atomicAdd(&accx[j], f.x); atomicAdd(&accy[j], f.y);
        }
    }
    __syncthreads();
    int base = b << SHIFT;
    for (int j = threadIdx.x; j < NB; j += blockDim.x) {
        int node = base + j;
        if (node >= nn) continue;
        float di = dinv[node];
        float2 self = __half22float2(feat[node]);
        float ax = di * (accx[j] + self.x);
        float ay = di * (accy[j] + self.y);
        if (LAYER == 1) {
            float o0 = 0.f, o1 = 0.f;
#pragma unroll
            for (int k = 0; k < 8; ++k) {
                float hk = fmaxf(ax * W1[k] + ay * W1[8 + k] + b1[k], 0.f);
                o0 += hk * W2[2 * k + 0];
                o1 += hk * W2[2 * k + 1];
            }
            out_h2[node] = __floats2half2_rn(o0 * di, o1 * di);
        } else {
            out_f2[node] = make_float2(ax + b2[0], ay + b2[1]);
        }
    }
    if (LAYER == 1 && b == 0 && threadIdx.x == 0)
        out_h2[nn] = __floats2half2_rn(0.f, 0.f);
}

// ---------- fallback (round-1 algorithm, ~24 MB scratch) ----------

__global__ void k_deg(const int* __restrict__ dst, int* __restrict__ deg, int ne) {
    int i = blockIdx.x * blockDim.x + threadIdx.x;
    int stride = gridDim.x * blockDim.x;
    for (; i < ne; i += stride) atomicAdd(&deg[dst[i]], 1);
}
__global__ void k_dinv(const int* __restrict__ deg, float* __restrict__ dinv, int nn) {
    int i = blockIdx.x * blockDim.x + threadIdx.x;
    if (i < nn) dinv[i] = rsqrtf((float)(deg[i] + 1));
}
__global__ void k_edge2(const int* __restrict__ src, const int* __restrict__ dst,
                        const float* __restrict__ feat2, const float* __restrict__ dinv,
                        float* __restrict__ agg2, int ne) {
    int i = blockIdx.x * blockDim.x + threadIdx.x;
    int stride = gridDim.x * blockDim.x;
    for (; i < ne; i += stride) {
        int s = src[i], d = dst[i];
        float nrm = dinv[s] * dinv[d];
        float2 f = reinterpret_cast<const float2*>(feat2)[s];
        unsafeAtomicAdd(&agg2[2 * d + 0], nrm * f.x);
        unsafeAtomicAdd(&agg2[2 * d + 1], nrm * f.y);
    }
}
__global__ void k_mid(const float* __restrict__ x, const float* __restrict__ aggx,
                      const float* __restrict__ dinv,
                      const float* __restrict__ W1, const float* __restrict__ b1,
                      const float* __restrict__ W2, float* __restrict__ a2, int nn) {
    int i = blockIdx.x * blockDim.x + threadIdx.x;
    if (i >= nn) return;
    float di = dinv[i], di2 = di * di;
    float2 xsv = reinterpret_cast<const float2*>(x)[i];
    float ax = aggx[2 * i + 0] + di2 * xsv.x;
    float ay = aggx[2 * i + 1] + di2 * xsv.y;
    float o0 = 0.f, o1 = 0.f;
#pragma unroll
    for (int k = 0; k < 8; ++k) {
        float hk = fmaxf(ax * W1[k] + ay * W1[8 + k] + b1[k], 0.f);
        o0 += hk * W2[2 * k + 0];
        o1 += hk * W2[2 * k + 1];
    }
    a2[2 * i + 0] = o0;
    a2[2 * i + 1] = o1;
}
__global__ void k_out(const float* __restrict__ a2, const float* __restrict__ dinv,
                      const float* __restrict__ b2, float* __restrict__ out, int nn) {
    int i = blockIdx.x * blockDim.x + threadIdx.x;
    if (i >= nn) return;
    float di = dinv[i], di2 = di * di;
    out[2 * i + 0] = out[2 * i + 0] + di2 * a2[2 * i + 0] + b2[0];
    out[2 * i + 1] = out[2 * i + 1] + di2 * a2[2 * i + 1] + b2[1];
}

extern "C" void kernel_launch(void* const* d_in, const int* in_sizes, int n_in,
                              void* d_out, int out_size, void* d_ws, size_t ws_size,
                              hipStream_t stream) {
    const float* x  = (const float*)d_in[0];
    const int*   ei = (const int*)d_in[1];
    const float* W1 = (const float*)d_in[2];
    const float* b1 = (const float*)d_in[3];
    const float* W2 = (const float*)d_in[4];
    const float* b2 = (const float*)d_in[5];
    float* out = (float*)d_out;

    const int nn = in_sizes[0] / 2;
    const int ne = in_sizes[1] / 2;
    const int* src = ei;
    const int* dst = ei + ne;

    char* ws = (char*)d_ws;
    size_t off = 0;
    auto alloc = [&](size_t bytes) -> void* {
        void* p = ws + off;
        off += (bytes + 255) & ~size_t(255);
        return p;
    };

    int nc = (ne + EPW - 1) / EPW;
    size_t sorted_elems = (size_t)ne + (size_t)nc * NB * 16;   // worst-case pads
    size_t need = sorted_elems * 4 + (size_t)nn * 4 + 2 * ((size_t)nn + 1) * 4
                + (size_t)nc * NB * 4 + (2 * NB + 2) * 4 + 16384;

    if (ws_size >= need && nc <= 1024) {
        unsigned* sorted = (unsigned*)alloc(sorted_elems * 4);
        float*    dinv   = (float*)   alloc((size_t)nn * 4);
        __half2*  xs     = (__half2*) alloc(((size_t)nn + 1) * 4);
        __half2*  xs2    = (__half2*) alloc(((size_t)nn + 1) * 4);
        int*      ghist  = (int*)     alloc((size_t)nc * NB * 4);
        int*      tot    = (int*)     alloc(NB * 4);
        int*      start  = (int*)     alloc((NB + 1) * 4);

        unsigned sentbase = 0x80000000u | ((unsigned)nn << SHIFT);

        h_hist   <<<nc, BLK, 0, stream>>>(dst, ne, ghist);
        h_colscan<<<NB, 256, 0, stream>>>(ghist, tot, nc);
        s_scan   <<<1, NB, 0, stream>>>(tot, start);
        h_scatter<<<nc, BLK, 0, stream>>>(src, dst, ne, ghist, start, sorted, sentbase);
        s_deg    <<<NB, 512, 0, stream>>>(sorted, start, (const float2*)x, dinv, xs, nn);
        s_agg<1> <<<NB, 512, 0, stream>>>(sorted, start, xs, dinv, W1, b1, W2, b2,
                                          xs2, nullptr, nn);
        s_agg<2> <<<NB, 512, 0, stream>>>(sorted, start, xs2, dinv, W1, b1, W2, b2,
                                          nullptr, (float2*)out, nn);
    } else {
        // fallback: round-1 algorithm
        int*   deg  = (int*)  alloc((size_t)nn * 4);
        float* dinv = (float*)alloc((size_t)nn * 4);
        float* aggx = (float*)alloc((size_t)nn * 8);
        float* a2   = (float*)alloc((size_t)nn * 8);
        hipMemsetAsync(deg,  0, (size_t)nn * 4, stream);
        hipMemsetAsync(aggx, 0, (size_t)nn * 8, stream);
        hipMemsetAsync(d_out, 0, (size_t)nn * 8, stream);
        const int TB = 256;
        int egrid = (ne + TB - 1) / TB;
        int ngrid = (nn + TB - 1) / TB;
        k_deg  <<<egrid, TB, 0, stream>>>(dst, deg, ne);
        k_dinv <<<ngrid, TB, 0, stream>>>(deg, dinv, nn);
        k_edge2<<<egrid, TB, 0, stream>>>(src, dst, x, dinv, aggx, ne);
        k_mid  <<<ngrid, TB, 0, stream>>>(x, aggx, dinv, W1, b1, W2, a2, nn);
        k_edge2<<<egrid, TB, 0, stream>>>(src, dst, a2, dinv, out, ne);
        k_out  <<<ngrid, TB, 0, stream>>>(a2, dinv, b2, out, nn);
    }
}